// Round 4
// baseline (236.383 us; speedup 1.0000x reference)
//
#include <hip/hip_runtime.h>
#include <hip/hip_bf16.h>
#include <hip/hip_cooperative_groups.h>
#include <stdint.h>

namespace cg = cooperative_groups;

// SimCLR loss, B=4096, D=256, T=0.1 — single cooperative persistent kernel.
// loss = (1/2B) * sum_i [ log(sum_{j!=i} exp(sim_ij)) - sim_{i,pair(i)} ]
// sim in [-10,10] => no max-subtraction needed.
// Symmetric Gram: lower-triangle 128x128 tiles (2080); off-diag tiles add
// row sums to rowsum[i] and col sums to rowsum[j].
// 512 blocks (2/CU @ 64KB LDS). Block p does tiles p, p+512, ... so the
// co-resident tile-id window is consecutive -> R2's L2 locality (~94% hit).
// K-chunks (A 16KB + B 16KB) double-buffered; prefetch issued AFTER the
// barrier so the barrier drains only the chunk being consumed.

#define BROWS 4096
#define NROWS 8192
#define DDIM  256
#define TINV  10.0f
#define EPSN  1e-8f

#define TM    128
#define BKC   64
#define NTILE (NROWS / TM)               // 64
#define NTRI  (NTILE * (NTILE + 1) / 2)  // 2080
#define GRIDN 512

typedef __bf16 bf16;
typedef bf16  bf16x4 __attribute__((ext_vector_type(4)));
typedef bf16  bf16x8 __attribute__((ext_vector_type(8)));
typedef float f32x4  __attribute__((ext_vector_type(4)));

__device__ __forceinline__ void async16(const bf16* g, bf16* l) {
  __builtin_amdgcn_global_load_lds(
      (const __attribute__((address_space(1))) unsigned int*)g,
      (__attribute__((address_space(3))) unsigned int*)l,
      16, 0, 0);
}

__device__ __forceinline__ void decode_tri(int tid, int& bi, int& bj) {
  int x = (int)((sqrtf(8.0f * tid + 1.0f) - 1.0f) * 0.5f);
  while ((x + 1) * (x + 2) / 2 <= tid) ++x;
  while (x * (x + 1) / 2 > tid) --x;
  bi = x; bj = tid - x * (x + 1) / 2;
}

__global__ __launch_bounds__(256, 2) void simclr_kernel(
    const float* __restrict__ z1, const float* __restrict__ z2,
    bf16* __restrict__ zn, float* __restrict__ pos,
    float* __restrict__ rowsum, float* __restrict__ out) {
  __shared__ __align__(16) bf16 ldsA[2][TM * BKC];   // 2 x 16 KB
  __shared__ __align__(16) bf16 ldsB[2][TM * BKC];   // 2 x 16 KB

  const int b = blockIdx.x, t = threadIdx.x;
  const int wave = t >> 6, lane = t & 63;
  const int wr = wave >> 1, wc = wave & 1;
  const int quad = lane >> 4, l15 = lane & 15;

  // ---------------- phase 1: prep (norms, bf16 rows, pos, zeroing) --------
  if (b < 32) rowsum[b * 256 + t] = 0.f;
  if (b == 32 && t == 0) out[0] = 0.f;
  #pragma unroll
  for (int r = 0; r < 2; ++r) {
    int i = b * 8 + wave * 2 + r;            // 512*8 = 4096 pair-rows
    float4 a = ((const float4*)(z1 + (size_t)i * DDIM))[lane];
    float4 bb = ((const float4*)(z2 + (size_t)i * DDIM))[lane];
    float s1 = a.x*a.x + a.y*a.y + a.z*a.z + a.w*a.w;
    float s2 = bb.x*bb.x + bb.y*bb.y + bb.z*bb.z + bb.w*bb.w;
    float dt = a.x*bb.x + a.y*bb.y + a.z*bb.z + a.w*bb.w;
    #pragma unroll
    for (int off = 32; off; off >>= 1) {
      s1 += __shfl_xor(s1, off, 64);
      s2 += __shfl_xor(s2, off, 64);
      dt += __shfl_xor(dt, off, 64);
    }
    float i1 = 1.0f / fmaxf(sqrtf(s1), EPSN);
    float i2 = 1.0f / fmaxf(sqrtf(s2), EPSN);
    if (lane == 0) pos[i] = dt * i1 * i2 * TINV;
    bf16x4 o1, o2;
    o1[0] = (bf16)(a.x*i1);  o1[1] = (bf16)(a.y*i1);
    o1[2] = (bf16)(a.z*i1);  o1[3] = (bf16)(a.w*i1);
    o2[0] = (bf16)(bb.x*i2); o2[1] = (bf16)(bb.y*i2);
    o2[2] = (bf16)(bb.z*i2); o2[3] = (bf16)(bb.w*i2);
    *(bf16x4*)(zn + (size_t)i * DDIM + lane * 4) = o1;
    *(bf16x4*)(zn + (size_t)(i + BROWS) * DDIM + lane * 4) = o2;
  }

  cg::this_grid().sync();

  // ---------------- phase 2: Gram tiles + exp + row/col sums --------------
  const int nt = (NTRI - b + GRIDN - 1) / GRIDN;   // 4 or 5 tiles
  const int NCH = nt * 4;                          // 64-K chunks total

  // stage chunk c: tile (c>>2)*GRIDN + b, K-chunk c&3, buffer c&1.
  // XOR swizzle folded into the global address (global_load_lds LDS dest
  // must be wave-uniform base + lane*16).
  auto stage = [&](int c) {
    int tid = (c >> 2) * GRIDN + b;
    if (tid >= NTRI) return;
    int bi, bj; decode_tri(tid, bi, bj);
    int kc = c & 3, buf = c & 1;
    const bf16* baseA = zn + (size_t)bi * TM * DDIM + kc * BKC;
    const bf16* baseB = zn + (size_t)bj * TM * DDIM + kc * BKC;
    #pragma unroll
    for (int p = 0; p < 4; ++p) {
      int j = p * 256 + t;
      int row = j >> 3, c8 = j & 7;
      int gc8 = c8 ^ (row & 7);
      async16(baseA + (size_t)row * DDIM + gc8 * 8, &ldsA[buf][j * 8]);
      async16(baseB + (size_t)row * DDIM + gc8 * 8, &ldsB[buf][j * 8]);
    }
  };

  f32x4 acc[4][4] = {};
  stage(0);
  for (int c = 0; c < NCH; ++c) {
    __syncthreads();                      // drains DMA for chunk c only
    if (c + 1 < NCH) stage(c + 1);        // prefetch lands during compute

    const int buf = c & 1;
    #pragma unroll
    for (int kk = 0; kk < 2; ++kk) {
      const int kc8 = kk * 4 + quad;
      bf16x8 af[4], bg[4];
      #pragma unroll
      for (int mi = 0; mi < 4; ++mi) {
        int row = wr * 64 + mi * 16 + l15;
        int sc8 = kc8 ^ (row & 7);
        af[mi] = *(const bf16x8*)&ldsA[buf][(row * 8 + sc8) * 8];
      }
      #pragma unroll
      for (int nj = 0; nj < 4; ++nj) {
        int row = wc * 64 + nj * 16 + l15;
        int sc8 = kc8 ^ (row & 7);
        bg[nj] = *(const bf16x8*)&ldsB[buf][(row * 8 + sc8) * 8];
      }
      #pragma unroll
      for (int mi = 0; mi < 4; ++mi)
        #pragma unroll
        for (int nj = 0; nj < 4; ++nj)
          acc[mi][nj] = __builtin_amdgcn_mfma_f32_16x16x32_bf16(
              af[mi], bg[nj], acc[mi][nj], 0, 0, 0);
    }

    if ((c & 3) == 3) {                   // tile finished: epilogue
      int tid = (c >> 2) * GRIDN + b;
      int bi, bj; decode_tri(tid, bi, bj);
      const int rowA0 = bi * TM, rowB0 = bj * TM;
      float cs[4] = {0.f, 0.f, 0.f, 0.f};
      #pragma unroll
      for (int mi = 0; mi < 4; ++mi) {
        float rs[4] = {0.f, 0.f, 0.f, 0.f};
        #pragma unroll
        for (int nj = 0; nj < 4; ++nj) {
          int gj = rowB0 + wc * 64 + nj * 16 + l15;
          #pragma unroll
          for (int r = 0; r < 4; ++r) {
            int gi = rowA0 + wr * 64 + mi * 16 + quad * 4 + r;
            float e = (gi == gj) ? 0.f : __expf(acc[mi][nj][r] * TINV);
            rs[r] += e;
            cs[nj] += e;
            acc[mi][nj][r] = 0.f;         // reset for next tile
          }
        }
        #pragma unroll
        for (int r = 0; r < 4; ++r) {
          float v = rs[r];
          v += __shfl_xor(v, 1, 64);
          v += __shfl_xor(v, 2, 64);
          v += __shfl_xor(v, 4, 64);
          v += __shfl_xor(v, 8, 64);
          if (l15 == 0)
            atomicAdd(&rowsum[rowA0 + wr * 64 + mi * 16 + quad * 4 + r], v);
        }
      }
      if (bi != bj) {                     // symmetry: column sums
        #pragma unroll
        for (int nj = 0; nj < 4; ++nj) {
          float v = cs[nj];
          v += __shfl_xor(v, 16, 64);
          v += __shfl_xor(v, 32, 64);
          if (quad == 0)
            atomicAdd(&rowsum[rowB0 + wc * 64 + nj * 16 + l15], v);
        }
      }
    }
  }

  cg::this_grid().sync();

  // ---------------- phase 3: final scalar reduction -----------------------
  float v = 0.f;
  if (t < 16) {
    int idx = b * 16 + t;                 // 512*16 = 8192 rows
    v = __logf(rowsum[idx]);
    if (idx < BROWS) v -= 2.f * pos[idx];
  }
  if (wave == 0) {
    v += __shfl_xor(v, 1, 64);
    v += __shfl_xor(v, 2, 64);
    v += __shfl_xor(v, 4, 64);
    v += __shfl_xor(v, 8, 64);
    if (lane == 0) atomicAdd(out, v / (float)NROWS);
  }
}

// ---------------- launch ----------------------------------------------------
extern "C" void kernel_launch(void* const* d_in, const int* in_sizes, int n_in,
                              void* d_out, int out_size, void* d_ws, size_t ws_size,
                              hipStream_t stream) {
  const float* z1 = (const float*)d_in[0];
  const float* z2 = (const float*)d_in[1];
  char* ws = (char*)d_ws;
  bf16*  zn     = (bf16*)ws;                               // 4 MB
  float* rowsum = (float*)(ws + 4194304);                  // 32 KB
  float* pos    = (float*)(ws + 4194304 + 32768);          // 16 KB
  float* out    = (float*)d_out;

  void* args[] = { (void*)&z1, (void*)&z2, (void*)&zn,
                   (void*)&pos, (void*)&rowsum, (void*)&out };
  hipLaunchCooperativeKernel((const void*)simclr_kernel,
                             dim3(GRIDN), dim3(256), args, 0, stream);
}

// Round 5
// 113.937 us; speedup vs baseline: 2.0747x; 2.0747x over previous
//
#include <hip/hip_runtime.h>
#include <hip/hip_bf16.h>
#include <stdint.h>

// SimCLR loss, B=4096, D=256, T=0.1.
// loss = (1/2B) * sum_i [ log(sum_{j!=i} exp(sim_ij)) - sim_{i,pair(i)} ]
// sim in [-10,10] => no max-subtraction needed.
// Gram in FP8 e4m3 (positive-pair term exact fp32): full K=256 row = 256 B,
// so a 128x128 tile stages A+B = 64 KB LDS in ONE shot -> one barrier per
// tile (the multi-chunk barrier drain was the R1-R4 bottleneck).
// Symmetric: lower-triangle tiles only (2080); off-diag tiles add row sums
// to rowsum[i] and col sums to rowsum[j].

#define BROWS 4096
#define NROWS 8192
#define DDIM  256
#define TINV  10.0f
#define EPSN  1e-8f

#define TM    128
#define NTILE (NROWS / TM)               // 64
#define NTRI  (NTILE * (NTILE + 1) / 2)  // 2080

typedef float f32x4 __attribute__((ext_vector_type(4)));

// ------- prep: norms + fp8 unit rows + positive logits + zeroing ----------
__global__ __launch_bounds__(256) void prep_kernel(
    const float* __restrict__ z1, const float* __restrict__ z2,
    unsigned int* __restrict__ zn8, float* __restrict__ pos,
    float* __restrict__ rowsum, float* __restrict__ out) {
  int t = threadIdx.x;
  int i    = blockIdx.x * 4 + (t >> 6);
  int lane = t & 63;
  if (blockIdx.x < 32) rowsum[blockIdx.x * 256 + t] = 0.f;
  if (blockIdx.x == 32 && t == 0) out[0] = 0.f;

  float4 a = ((const float4*)(z1 + (size_t)i * DDIM))[lane];
  float4 b = ((const float4*)(z2 + (size_t)i * DDIM))[lane];
  float s1 = a.x*a.x + a.y*a.y + a.z*a.z + a.w*a.w;
  float s2 = b.x*b.x + b.y*b.y + b.z*b.z + b.w*b.w;
  float dt = a.x*b.x + a.y*b.y + a.z*b.z + a.w*b.w;
  #pragma unroll
  for (int off = 32; off; off >>= 1) {
    s1 += __shfl_xor(s1, off, 64);
    s2 += __shfl_xor(s2, off, 64);
    dt += __shfl_xor(dt, off, 64);
  }
  float i1 = 1.0f / fmaxf(sqrtf(s1), EPSN);
  float i2 = 1.0f / fmaxf(sqrtf(s2), EPSN);
  if (lane == 0) pos[i] = dt * i1 * i2 * TINV;
  // pack 4 normalized floats -> 4 fp8 e4m3 bytes (one dword per lane)
  int p1 = __builtin_amdgcn_cvt_pk_fp8_f32(a.x*i1, a.y*i1, 0, false);
  p1     = __builtin_amdgcn_cvt_pk_fp8_f32(a.z*i1, a.w*i1, p1, true);
  int p2 = __builtin_amdgcn_cvt_pk_fp8_f32(b.x*i2, b.y*i2, 0, false);
  p2     = __builtin_amdgcn_cvt_pk_fp8_f32(b.z*i2, b.w*i2, p2, true);
  zn8[(size_t)i * 64 + lane]           = (unsigned int)p1;
  zn8[(size_t)(i + BROWS) * 64 + lane] = (unsigned int)p2;
}

// ---------------- async global->LDS, 16B ----------------------------------
__device__ __forceinline__ void async16(const unsigned char* g, unsigned char* l) {
  __builtin_amdgcn_global_load_lds(
      (const __attribute__((address_space(1))) unsigned int*)g,
      (__attribute__((address_space(3))) unsigned int*)l,
      16, 0, 0);
}

__device__ __forceinline__ void decode_tri(int tid, int& bi, int& bj) {
  int x = (int)((sqrtf(8.0f * tid + 1.0f) - 1.0f) * 0.5f);
  while ((x + 1) * (x + 2) / 2 <= tid) ++x;
  while (x * (x + 1) / 2 > tid) --x;
  bi = x; bj = tid - x * (x + 1) / 2;
}

// ---------------- one-shot fp8 Gram tile + exp + row/col sums --------------
// LDS row = 256 B = 16 granules of 16 B; granule slot g holds global granule
// (g ^ (row&15)) -> swizzle folded into global addr (global_load_lds needs
// wave-uniform LDS base + lane*16), ds_read_b64 lands 2-way on banks (free).
__global__ __launch_bounds__(256) void simexp_kernel(
    const unsigned char* __restrict__ zn8, float* __restrict__ rowsum) {
  __shared__ __align__(16) unsigned char ldsA[TM * 256];   // 32 KB
  __shared__ __align__(16) unsigned char ldsB[TM * 256];   // 32 KB

  int bi, bj;
  decode_tri(blockIdx.x, bi, bj);

  const int t = threadIdx.x;
  const int wave = t >> 6, lane = t & 63;
  const int wr = wave >> 1, wc = wave & 1;
  const int quad = lane >> 4, l15 = lane & 15;
  const int rowA0 = bi * TM, rowB0 = bj * TM;

  // ---- stage the whole tile pair in one shot: 2048 granules each --------
  const unsigned char* baseA = zn8 + (size_t)rowA0 * 256;
  const unsigned char* baseB = zn8 + (size_t)rowB0 * 256;
  #pragma unroll
  for (int p = 0; p < 8; ++p) {
    int j = p * 256 + t;                  // granule index 0..2047
    int row = j >> 4, g = j & 15;
    int gg = g ^ (row & 15);              // swizzle in global address
    size_t goff = (size_t)row * 256 + gg * 16;
    async16(baseA + goff, &ldsA[j * 16]);
    async16(baseB + goff, &ldsB[j * 16]);
  }
  __syncthreads();                        // the ONLY barrier

  // ---- full-K MFMA: 8 k-steps x 4x4 frags = 128 MFMA per wave -----------
  f32x4 acc[4][4] = {};
  #pragma unroll
  for (int ks = 0; ks < 8; ++ks) {
    // lane wants k bytes [ks*32 + quad*8 .. +8) = granule ks*2 + (quad>>1),
    // sub-offset (quad&1)*8
    const int gr  = ks * 2 + (quad >> 1);
    const int sub = (quad & 1) * 8;
    long af[4], bg[4];
    #pragma unroll
    for (int mi = 0; mi < 4; ++mi) {
      int row = wr * 64 + mi * 16 + l15;
      af[mi] = *(const long*)&ldsA[row * 256 + (gr ^ (row & 15)) * 16 + sub];
    }
    #pragma unroll
    for (int nj = 0; nj < 4; ++nj) {
      int row = wc * 64 + nj * 16 + l15;
      bg[nj] = *(const long*)&ldsB[row * 256 + (gr ^ (row & 15)) * 16 + sub];
    }
    #pragma unroll
    for (int mi = 0; mi < 4; ++mi)
      #pragma unroll
      for (int nj = 0; nj < 4; ++nj)
        acc[mi][nj] = __builtin_amdgcn_mfma_f32_16x16x32_fp8_fp8(
            af[mi], bg[nj], acc[mi][nj], 0, 0, 0);
  }

  // ---- epilogue: exp (diag masked), row sums + (off-diag) col sums ------
  float cs[4] = {0.f, 0.f, 0.f, 0.f};
  #pragma unroll
  for (int mi = 0; mi < 4; ++mi) {
    float rs[4] = {0.f, 0.f, 0.f, 0.f};
    #pragma unroll
    for (int nj = 0; nj < 4; ++nj) {
      int gj = rowB0 + wc * 64 + nj * 16 + l15;
      #pragma unroll
      for (int r = 0; r < 4; ++r) {
        int gi = rowA0 + wr * 64 + mi * 16 + quad * 4 + r;
        float e = (gi == gj) ? 0.f : __expf(acc[mi][nj][r] * TINV);
        rs[r] += e;
        cs[nj] += e;
      }
    }
    #pragma unroll
    for (int r = 0; r < 4; ++r) {
      float v = rs[r];
      v += __shfl_xor(v, 1, 64);
      v += __shfl_xor(v, 2, 64);
      v += __shfl_xor(v, 4, 64);
      v += __shfl_xor(v, 8, 64);
      if (l15 == 0)
        atomicAdd(&rowsum[rowA0 + wr * 64 + mi * 16 + quad * 4 + r], v);
    }
  }
  if (bi != bj) {
    #pragma unroll
    for (int nj = 0; nj < 4; ++nj) {
      float v = cs[nj];
      v += __shfl_xor(v, 16, 64);
      v += __shfl_xor(v, 32, 64);
      if (quad == 0)
        atomicAdd(&rowsum[rowB0 + wc * 64 + nj * 16 + l15], v);
    }
  }
}

// ---------------- final scalar reduction (32 blocks) -----------------------
__global__ __launch_bounds__(256) void finalize_kernel(
    const float* __restrict__ rowsum, const float* __restrict__ pos,
    float* __restrict__ out) {
  __shared__ float red[4];
  int t = threadIdx.x;
  int idx = blockIdx.x * 256 + t;
  float s = __logf(rowsum[idx]);
  if (idx < BROWS) s -= 2.f * pos[idx];
  #pragma unroll
  for (int off = 32; off; off >>= 1) s += __shfl_xor(s, off, 64);
  if ((t & 63) == 0) red[t >> 6] = s;
  __syncthreads();
  if (t == 0)
    atomicAdd(out, (red[0] + red[1] + red[2] + red[3]) / (float)NROWS);
}

// ---------------- launch ----------------------------------------------------
extern "C" void kernel_launch(void* const* d_in, const int* in_sizes, int n_in,
                              void* d_out, int out_size, void* d_ws, size_t ws_size,
                              hipStream_t stream) {
  const float* z1 = (const float*)d_in[0];
  const float* z2 = (const float*)d_in[1];
  char* ws = (char*)d_ws;
  unsigned int* zn8 = (unsigned int*)ws;                   // 2 MB (fp8 rows)
  float* rowsum = (float*)(ws + 2097152);                  // 32 KB
  float* pos    = (float*)(ws + 2097152 + 32768);          // 16 KB
  float* out    = (float*)d_out;

  prep_kernel<<<BROWS / 4, 256, 0, stream>>>(z1, z2, zn8, pos, rowsum, out);
  simexp_kernel<<<NTRI, 256, 0, stream>>>((const unsigned char*)zn8, rowsum);
  finalize_kernel<<<NROWS / 256, 256, 0, stream>>>(rowsum, pos, out);
}